// Round 1
// baseline (347.763 us; speedup 1.0000x reference)
//
#include <hip/hip_runtime.h>
#include <math.h>

// ---------------------------------------------------------------------------
// TransformerBlock: B=2, S=2048, D=512, H=8, HD=64, DFF=2048, fp32 in/out.
// bf16 MFMA (16x16x32) for all matmuls. Verified layouts (cdna_hip guide §3):
//   A-frag:  A[m = lane&15][k = (lane>>4)*8 + j]   (8 contiguous bf16)
//   B-frag:  B[n = lane&15][k = (lane>>4)*8 + j]   (B^T layout, i.e. W[N][K])
//   C/D:     col = lane&15, row = (lane>>4)*4 + reg
// ---------------------------------------------------------------------------

typedef __bf16 bf16x8 __attribute__((ext_vector_type(8)));
typedef float  f32x4  __attribute__((ext_vector_type(4)));

#define TOKENS 4096   // B*S
#define DMODEL 512
#define NHEADS 8
#define HDIM   64
#define DFF    2048
#define SEQ    2048

// ---------------- fp32 -> bf16 convert (weights) ----------------
__global__ void cvt_f32_bf16(const float* __restrict__ src, __bf16* __restrict__ dst, int n) {
    int i = (blockIdx.x * blockDim.x + threadIdx.x) * 4;
    if (i < n) {
        float4 v = *(const float4*)&src[i];
        dst[i + 0] = (__bf16)v.x;
        dst[i + 1] = (__bf16)v.y;
        dst[i + 2] = (__bf16)v.z;
        dst[i + 3] = (__bf16)v.w;
    }
}

// ---------------- RMSNorm: fp32 in -> bf16 out. one wave per token ----------
__global__ void rmsnorm_kernel(const float* __restrict__ x, const float* __restrict__ scale,
                               __bf16* __restrict__ out) {
    int wave = threadIdx.x >> 6, lane = threadIdx.x & 63;
    int tok = blockIdx.x * 4 + wave;
    const float* row = x + (size_t)tok * DMODEL;
    float4 v0 = *(const float4*)&row[lane * 4];
    float4 v1 = *(const float4*)&row[256 + lane * 4];
    float ss = v0.x*v0.x + v0.y*v0.y + v0.z*v0.z + v0.w*v0.w
             + v1.x*v1.x + v1.y*v1.y + v1.z*v1.z + v1.w*v1.w;
    #pragma unroll
    for (int off = 1; off < 64; off <<= 1) ss += __shfl_xor(ss, off);
    float r = rsqrtf(ss * (1.0f / DMODEL) + 1e-8f);
    __bf16* o = out + (size_t)tok * DMODEL;
    const float* sc0 = scale + lane * 4;
    o[lane*4 + 0] = (__bf16)(v0.x * r * sc0[0]);
    o[lane*4 + 1] = (__bf16)(v0.y * r * sc0[1]);
    o[lane*4 + 2] = (__bf16)(v0.z * r * sc0[2]);
    o[lane*4 + 3] = (__bf16)(v0.w * r * sc0[3]);
    o[256 + lane*4 + 0] = (__bf16)(v1.x * r * scale[256 + lane*4 + 0]);
    o[256 + lane*4 + 1] = (__bf16)(v1.y * r * scale[256 + lane*4 + 1]);
    o[256 + lane*4 + 2] = (__bf16)(v1.z * r * scale[256 + lane*4 + 2]);
    o[256 + lane*4 + 3] = (__bf16)(v1.w * r * scale[256 + lane*4 + 3]);
}

// ---------------- GEMM: C[M,N] = A[M,K](bf16) @ W[N,K](bf16)^T + bias -------
// EPI: 0 = fp32 C+bias        (qkv)
//      1 = fp32 res + C+bias  (x1 = x + attn_out)
//      2 = bf16 gelu(C+bias)  (h)
//      3 = fp32 res + C+bias  (final out)
// 128x128 tile, BK=32, 256 threads (4 waves, 2x2), wave does 64x64 (4x4 mfma).
template <int EPI>
__global__ __launch_bounds__(256) void gemm_bt(
    const __bf16* __restrict__ A, const __bf16* __restrict__ W,
    const float* __restrict__ bias, const float* __restrict__ res,
    float* __restrict__ Cf, __bf16* __restrict__ Cb,
    int M, int N, int K)
{
    __shared__ __bf16 As[128][40];
    __shared__ __bf16 Bs[128][40];
    const int tid = threadIdx.x;
    const int bm = blockIdx.x * 128;
    const int bn = blockIdx.y * 128;
    const int wave = tid >> 6, lane = tid & 63;
    const int wm = (wave & 1) * 64, wn = (wave >> 1) * 64;
    const int lrow = lane & 15;
    const int kq = (lane >> 4) * 8;

    f32x4 acc[4][4] = {};

    const int r0 = tid >> 2,        c80 = (tid & 3) * 8;
    const int r1 = (tid + 256) >> 2, c81 = c80; // (tid+256)&3 == tid&3

    for (int k0 = 0; k0 < K; k0 += 32) {
        __syncthreads();
        *(int4*)&As[r0][c80] = *(const int4*)&A[(size_t)(bm + r0) * K + k0 + c80];
        *(int4*)&As[r1][c81] = *(const int4*)&A[(size_t)(bm + r1) * K + k0 + c81];
        *(int4*)&Bs[r0][c80] = *(const int4*)&W[(size_t)(bn + r0) * K + k0 + c80];
        *(int4*)&Bs[r1][c81] = *(const int4*)&W[(size_t)(bn + r1) * K + k0 + c81];
        __syncthreads();
        bf16x8 af[4], bf[4];
        #pragma unroll
        for (int i = 0; i < 4; i++) af[i] = *(bf16x8*)&As[wm + i*16 + lrow][kq];
        #pragma unroll
        for (int j = 0; j < 4; j++) bf[j] = *(bf16x8*)&Bs[wn + j*16 + lrow][kq];
        #pragma unroll
        for (int i = 0; i < 4; i++)
            #pragma unroll
            for (int j = 0; j < 4; j++)
                acc[i][j] = __builtin_amdgcn_mfma_f32_16x16x32_bf16(af[i], bf[j], acc[i][j], 0, 0, 0);
    }

    const int crow0 = (lane >> 4) * 4;
    const int ccol = lane & 15;
    #pragma unroll
    for (int i = 0; i < 4; i++) {
        #pragma unroll
        for (int j = 0; j < 4; j++) {
            const int col = bn + wn + j * 16 + ccol;
            const float bv = bias[col];
            #pragma unroll
            for (int r = 0; r < 4; r++) {
                const int row = bm + wm + i * 16 + crow0 + r;
                const size_t idx = (size_t)row * N + col;
                float v = acc[i][j][r] + bv;
                if (EPI == 0) {
                    Cf[idx] = v;
                } else if (EPI == 1) {
                    Cf[idx] = res[idx] + v;
                } else if (EPI == 2) {
                    float g = 0.5f * v * (1.0f + erff(v * 0.70710678f));
                    Cb[idx] = (__bf16)g;
                } else {
                    Cf[idx] = res[idx] + v;
                }
            }
        }
    }
}

// ---------------- Flash attention with ALiBi --------------------------------
// grid: (S/64, H, B); block 256 (4 waves); wave handles 16 q rows.
// qkv fp32 [B*S][1536]: q at h*64+d, k at 512+h*64+d, v at 1024+h*64+d.
__global__ __launch_bounds__(256) void attn_kernel(
    const float* __restrict__ qkv, __bf16* __restrict__ ctx)
{
    const int qt = blockIdx.x, h = blockIdx.y, b = blockIdx.z;
    const int tid = threadIdx.x, wave = tid >> 6, lane = tid & 63;
    const int lrow = lane & 15, quad = lane >> 4;

    __shared__ __bf16 Ks[32][72];      // K tile  [key][d]
    __shared__ __bf16 Vt[64][40];      // V tile transposed [d][key]
    __shared__ __bf16 Pt[4][16][40];   // per-wave P tile [q][key]

    const float slope = 1.0f / (float)(h + 1);   // alibi slopes for H=8
    const float scale = 0.125f;                  // 1/sqrt(64), folded into Q

    // preload this lane's Q A-fragments (2 d-halves of 32)
    bf16x8 qf[2];
    {
        const int qrow = qt * 64 + wave * 16 + lrow;
        const float* p0 = qkv + ((size_t)(b * SEQ + qrow)) * 1536 + h * 64;
        #pragma unroll
        for (int dh = 0; dh < 2; dh++) {
            const float* p = p0 + dh * 32 + quad * 8;
            #pragma unroll
            for (int j = 0; j < 8; j++) qf[dh][j] = (__bf16)(p[j] * scale);
        }
    }

    float m[4], l[4];
    f32x4 O[4] = {};
    #pragma unroll
    for (int r = 0; r < 4; r++) { m[r] = -1e30f; l[r] = 0.0f; }

    for (int kt = 0; kt < SEQ / 32; kt++) {
        __syncthreads();
        // stage K (bf16) and V^T (bf16): 32 keys x 64 dims each
        #pragma unroll
        for (int i = 0; i < 2; i++) {
            int c = tid + 256 * i;
            int row = c >> 4, d4 = (c & 15) * 4;
            const float* kp = qkv + ((size_t)(b * SEQ + kt * 32 + row)) * 1536 + 512 + h * 64 + d4;
            float4 kv = *(const float4*)kp;
            __bf16* kd = &Ks[row][d4];
            kd[0] = (__bf16)kv.x; kd[1] = (__bf16)kv.y; kd[2] = (__bf16)kv.z; kd[3] = (__bf16)kv.w;
            const float* vp = qkv + ((size_t)(b * SEQ + kt * 32 + row)) * 1536 + 1024 + h * 64 + d4;
            float4 vv = *(const float4*)vp;
            Vt[d4 + 0][row] = (__bf16)vv.x; Vt[d4 + 1][row] = (__bf16)vv.y;
            Vt[d4 + 2][row] = (__bf16)vv.z; Vt[d4 + 3][row] = (__bf16)vv.w;
        }
        __syncthreads();

        // S = (Q*scale) K^T  : two 16x16 C-tiles (32 keys)
        f32x4 Sc[2] = {};
        #pragma unroll
        for (int kt2 = 0; kt2 < 2; kt2++) {
            #pragma unroll
            for (int dh = 0; dh < 2; dh++) {
                bf16x8 kf = *(bf16x8*)&Ks[kt2 * 16 + lrow][dh * 32 + quad * 8];
                Sc[kt2] = __builtin_amdgcn_mfma_f32_16x16x32_bf16(qf[dh], kf, Sc[kt2], 0, 0, 0);
            }
        }

        // alibi + online softmax (rows = quad*4+r, col = lrow within tile)
        float alpha[4];
        #pragma unroll
        for (int r = 0; r < 4; r++) {
            const int qrow = qt * 64 + wave * 16 + quad * 4 + r;
            float rowm = -1e30f;
            #pragma unroll
            for (int kt2 = 0; kt2 < 2; kt2++) {
                int kcol = kt * 32 + kt2 * 16 + lrow;
                Sc[kt2][r] += -slope * fabsf((float)(qrow - kcol));
                rowm = fmaxf(rowm, Sc[kt2][r]);
            }
            #pragma unroll
            for (int off = 1; off < 16; off <<= 1)
                rowm = fmaxf(rowm, __shfl_xor(rowm, off));
            float mnew = fmaxf(m[r], rowm);
            alpha[r] = expf(m[r] - mnew);
            m[r] = mnew;
        }
        #pragma unroll
        for (int r = 0; r < 4; r++) {
            float rsum = 0.0f;
            #pragma unroll
            for (int kt2 = 0; kt2 < 2; kt2++) {
                float p = expf(Sc[kt2][r] - m[r]);
                rsum += p;
                Pt[wave][quad * 4 + r][kt2 * 16 + lrow] = (__bf16)p;
            }
            #pragma unroll
            for (int off = 1; off < 16; off <<= 1)
                rsum += __shfl_xor(rsum, off);
            l[r] = l[r] * alpha[r] + rsum;
        }
        __syncthreads();   // Pt write -> read visibility (and cheap)

        // O = O*alpha + P V  (P via LDS roundtrip into A-layout)
        bf16x8 pf = *(bf16x8*)&Pt[wave][lrow][quad * 8];
        #pragma unroll
        for (int dt = 0; dt < 4; dt++) {
            #pragma unroll
            for (int r = 0; r < 4; r++) O[dt][r] *= alpha[r];
            bf16x8 vf = *(bf16x8*)&Vt[dt * 16 + lrow][quad * 8];
            O[dt] = __builtin_amdgcn_mfma_f32_16x16x32_bf16(pf, vf, O[dt], 0, 0, 0);
        }
    }

    // epilogue: O/l -> ctx bf16 [tok][h*64+d]
    #pragma unroll
    for (int dt = 0; dt < 4; dt++) {
        #pragma unroll
        for (int r = 0; r < 4; r++) {
            const int qrow = qt * 64 + wave * 16 + quad * 4 + r;
            const int d = dt * 16 + lrow;
            ctx[((size_t)(b * SEQ + qrow)) * DMODEL + h * 64 + d] = (__bf16)(O[dt][r] / l[r]);
        }
    }
}

// ---------------------------------------------------------------------------
extern "C" void kernel_launch(void* const* d_in, const int* in_sizes, int n_in,
                              void* d_out, int out_size, void* d_ws, size_t ws_size,
                              hipStream_t stream) {
    const float* x    = (const float*)d_in[0];
    const float* n1s  = (const float*)d_in[1];
    const float* n2s  = (const float*)d_in[2];
    const float* wqkv = (const float*)d_in[3];
    const float* bqkv = (const float*)d_in[4];
    const float* wout = (const float*)d_in[5];
    const float* bout = (const float*)d_in[6];
    const float* w1   = (const float*)d_in[7];
    const float* b1   = (const float*)d_in[8];
    const float* w2   = (const float*)d_in[9];
    const float* b2   = (const float*)d_in[10];
    float* out = (float*)d_out;

    // workspace layout (~66 MB)
    char* ws = (char*)d_ws;
    __bf16* xn1    = (__bf16*)ws; ws += (size_t)TOKENS * DMODEL * 2;
    float*  qkv    = (float*)ws;  ws += (size_t)TOKENS * 1536 * 4;
    __bf16* wqkv_b = (__bf16*)ws; ws += (size_t)1536 * DMODEL * 2;
    __bf16* wout_b = (__bf16*)ws; ws += (size_t)DMODEL * DMODEL * 2;
    __bf16* w1_b   = (__bf16*)ws; ws += (size_t)DFF * DMODEL * 2;
    __bf16* w2_b   = (__bf16*)ws; ws += (size_t)DMODEL * DFF * 2;
    __bf16* ctx    = (__bf16*)ws; ws += (size_t)TOKENS * DMODEL * 2;
    float*  x1     = (float*)ws;  ws += (size_t)TOKENS * DMODEL * 4;
    __bf16* xn2    = (__bf16*)ws; ws += (size_t)TOKENS * DMODEL * 2;
    __bf16* hbuf   = (__bf16*)ws; ws += (size_t)TOKENS * DFF * 2;

    // 1) weight converts
    cvt_f32_bf16<<<dim3(1536 * DMODEL / 1024), 256, 0, stream>>>(wqkv, wqkv_b, 1536 * DMODEL);
    cvt_f32_bf16<<<dim3(DMODEL * DMODEL / 1024), 256, 0, stream>>>(wout, wout_b, DMODEL * DMODEL);
    cvt_f32_bf16<<<dim3(DFF * DMODEL / 1024), 256, 0, stream>>>(w1, w1_b, DFF * DMODEL);
    cvt_f32_bf16<<<dim3(DMODEL * DFF / 1024), 256, 0, stream>>>(w2, w2_b, DMODEL * DFF);

    // 2) rmsnorm1
    rmsnorm_kernel<<<dim3(TOKENS / 4), 256, 0, stream>>>(x, n1s, xn1);

    // 3) qkv = xn1 @ Wqkv^T + b  -> fp32
    gemm_bt<0><<<dim3(TOKENS / 128, 1536 / 128), 256, 0, stream>>>(
        xn1, wqkv_b, bqkv, nullptr, qkv, nullptr, TOKENS, 1536, DMODEL);

    // 4) attention -> ctx bf16
    attn_kernel<<<dim3(SEQ / 64, NHEADS, 2), 256, 0, stream>>>(qkv, ctx);

    // 5) x1 = x + ctx @ Wout^T + b
    gemm_bt<1><<<dim3(TOKENS / 128, DMODEL / 128), 256, 0, stream>>>(
        ctx, wout_b, bout, x, x1, nullptr, TOKENS, DMODEL, DMODEL);

    // 6) rmsnorm2
    rmsnorm_kernel<<<dim3(TOKENS / 4), 256, 0, stream>>>(x1, n2s, xn2);

    // 7) h = gelu(xn2 @ W1^T + b1) -> bf16
    gemm_bt<2><<<dim3(TOKENS / 128, DFF / 128), 256, 0, stream>>>(
        xn2, w1_b, b1, nullptr, nullptr, hbuf, TOKENS, DFF, DMODEL);

    // 8) out = x1 + h @ W2^T + b2
    gemm_bt<3><<<dim3(TOKENS / 128, DMODEL / 128), 256, 0, stream>>>(
        hbuf, w2_b, b2, x1, out, nullptr, TOKENS, DMODEL, DFF);
}

// Round 2
// 257.063 us; speedup vs baseline: 1.3528x; 1.3528x over previous
//
#include <hip/hip_runtime.h>
#include <math.h>

// ---------------------------------------------------------------------------
// TransformerBlock: B=2, S=2048, D=512, H=8, HD=64, DFF=2048, fp32 in/out.
// bf16 MFMA 16x16x32. Layouts (verified):
//   A-frag:  A[m = lane&15][k = (lane>>4)*8 + j]
//   B-frag:  B[n = lane&15][k = (lane>>4)*8 + j]   (i.e. W[N][K] row-major)
//   C/D:     col = lane&15, row = (lane>>4)*4 + reg
// All LDS tiles use 32-bf16 (64 B) rows => ds_read_b128 is 2-way-free.
// Staging via global_load_lds width 16 (wave-uniform base + lane*16).
// ---------------------------------------------------------------------------

typedef __bf16 bf16x8 __attribute__((ext_vector_type(8)));
typedef __bf16 bf16x4 __attribute__((ext_vector_type(4)));
typedef float  f32x4  __attribute__((ext_vector_type(4)));

#define TOKENS 4096
#define DMODEL 512
#define SEQ    2048

__device__ __forceinline__ void gl_lds16(const __bf16* g, __bf16* l) {
    __builtin_amdgcn_global_load_lds(
        (const __attribute__((address_space(1))) void*)g,
        (__attribute__((address_space(3))) void*)l, 16, 0, 0);
}

// ---------------- fp32 -> bf16 convert (weights) ----------------
__global__ void cvt_f32_bf16(const float* __restrict__ src, __bf16* __restrict__ dst, int n) {
    int i = (blockIdx.x * blockDim.x + threadIdx.x) * 4;
    if (i < n) {
        float4 v = *(const float4*)&src[i];
        dst[i + 0] = (__bf16)v.x;
        dst[i + 1] = (__bf16)v.y;
        dst[i + 2] = (__bf16)v.z;
        dst[i + 3] = (__bf16)v.w;
    }
}

// ---------------- RMSNorm: fp32 in -> bf16 out, one wave per token ----------
__global__ void rmsnorm_kernel(const float* __restrict__ x, const float* __restrict__ scale,
                               __bf16* __restrict__ out) {
    int wave = threadIdx.x >> 6, lane = threadIdx.x & 63;
    int tok = blockIdx.x * 4 + wave;
    const float* row = x + (size_t)tok * DMODEL;
    float4 v0 = *(const float4*)&row[lane * 4];
    float4 v1 = *(const float4*)&row[256 + lane * 4];
    float ss = v0.x*v0.x + v0.y*v0.y + v0.z*v0.z + v0.w*v0.w
             + v1.x*v1.x + v1.y*v1.y + v1.z*v1.z + v1.w*v1.w;
    #pragma unroll
    for (int off = 1; off < 64; off <<= 1) ss += __shfl_xor(ss, off);
    float r = rsqrtf(ss * (1.0f / DMODEL) + 1e-8f);
    __bf16* o = out + (size_t)tok * DMODEL;
    o[lane*4 + 0] = (__bf16)(v0.x * r * scale[lane*4 + 0]);
    o[lane*4 + 1] = (__bf16)(v0.y * r * scale[lane*4 + 1]);
    o[lane*4 + 2] = (__bf16)(v0.z * r * scale[lane*4 + 2]);
    o[lane*4 + 3] = (__bf16)(v0.w * r * scale[lane*4 + 3]);
    o[256 + lane*4 + 0] = (__bf16)(v1.x * r * scale[256 + lane*4 + 0]);
    o[256 + lane*4 + 1] = (__bf16)(v1.y * r * scale[256 + lane*4 + 1]);
    o[256 + lane*4 + 2] = (__bf16)(v1.z * r * scale[256 + lane*4 + 2]);
    o[256 + lane*4 + 3] = (__bf16)(v1.w * r * scale[256 + lane*4 + 3]);
}

// ---------------- GEMM: C[M,N] = A[M,K] @ W[N,K]^T + bias ------------------
// EPI: 1 = fp32 res + C + bias
//      2 = bf16 gelu(C+bias)
//      4 = qkv split: Q*0.125 -> qb[b,h,s,d], K -> kb[b,h,s,d], V -> vtb[b,h,d,s]
// TM x 128 tile, BK=64, 256 threads (4 waves), wave = (TM/2) x 64.
template <int EPI, int TM>
__global__ __launch_bounds__(256) void gemm_bt(
    const __bf16* __restrict__ A, const __bf16* __restrict__ W,
    const float* __restrict__ bias, const float* __restrict__ res,
    float* __restrict__ Cf, __bf16* __restrict__ Cb,
    __bf16* __restrict__ qb, __bf16* __restrict__ kb, __bf16* __restrict__ vtb,
    int M, int N, int K)
{
    constexpr int RI = TM / 32;                 // row mfma-tiles per wave
    __shared__ __bf16 As[2][TM * 32];           // [kh][m][32]
    __shared__ __bf16 Bs[2][128 * 32];          // [kh][n][32]
    const int tid = threadIdx.x;
    const int bm = blockIdx.x * TM;
    const int bn = blockIdx.y * 128;
    const int wave = tid >> 6, lane = tid & 63;
    const int wm = (wave & 1) * (TM / 2), wn = (wave >> 1) * 64;
    const int lrow = lane & 15;
    const int kq = (lane >> 4) * 8;

    f32x4 acc[RI][4] = {};

    for (int k0 = 0; k0 < K; k0 += 64) {
        __syncthreads();
        #pragma unroll
        for (int i = 0; i < TM / 32; i++) {
            int tt = i * 256 + tid;
            int kh = tt / (TM * 4), rem = tt % (TM * 4);
            int mrow = rem >> 2, c8 = rem & 3;
            gl_lds16(&A[(size_t)(bm + mrow) * K + k0 + kh * 32 + c8 * 8],
                     (__bf16*)As + tt * 8);
        }
        #pragma unroll
        for (int i = 0; i < 4; i++) {
            int tt = i * 256 + tid;
            int kh = tt >> 9, rem = tt & 511;
            int nrow = rem >> 2, c8 = rem & 3;
            gl_lds16(&W[(size_t)(bn + nrow) * K + k0 + kh * 32 + c8 * 8],
                     (__bf16*)Bs + tt * 8);
        }
        __syncthreads();
        #pragma unroll
        for (int kh = 0; kh < 2; kh++) {
            bf16x8 af[RI], bfv[4];
            #pragma unroll
            for (int i = 0; i < RI; i++) af[i] = *(bf16x8*)&As[kh][(wm + i*16 + lrow)*32 + kq];
            #pragma unroll
            for (int j = 0; j < 4; j++) bfv[j] = *(bf16x8*)&Bs[kh][(wn + j*16 + lrow)*32 + kq];
            #pragma unroll
            for (int i = 0; i < RI; i++)
                #pragma unroll
                for (int j = 0; j < 4; j++)
                    acc[i][j] = __builtin_amdgcn_mfma_f32_16x16x32_bf16(af[i], bfv[j], acc[i][j], 0, 0, 0);
        }
    }

    const int crow0 = (lane >> 4) * 4;
    const int ccol = lane & 15;
    #pragma unroll
    for (int i = 0; i < RI; i++) {
        const int row0 = bm + wm + i * 16 + crow0;
        #pragma unroll
        for (int j = 0; j < 4; j++) {
            const int col = bn + wn + j * 16 + ccol;
            const float bv = bias[col];
            if (EPI == 1) {
                #pragma unroll
                for (int r = 0; r < 4; r++) {
                    const size_t idx = (size_t)(row0 + r) * N + col;
                    Cf[idx] = res[idx] + acc[i][j][r] + bv;
                }
            } else if (EPI == 2) {
                #pragma unroll
                for (int r = 0; r < 4; r++) {
                    float v = acc[i][j][r] + bv;
                    Cb[(size_t)(row0 + r) * N + col] = (__bf16)(0.5f * v * (1.0f + erff(v * 0.70710678f)));
                }
            } else { // EPI == 4
                const int b = row0 >> 11, s0 = row0 & 2047;
                if (col < 512) {
                    const int h = col >> 6, d = col & 63;
                    #pragma unroll
                    for (int r = 0; r < 4; r++)
                        qb[(((size_t)b*8 + h)*2048 + s0 + r)*64 + d] = (__bf16)((acc[i][j][r] + bv) * 0.125f);
                } else if (col < 1024) {
                    const int h = (col - 512) >> 6, d = col & 63;
                    #pragma unroll
                    for (int r = 0; r < 4; r++)
                        kb[(((size_t)b*8 + h)*2048 + s0 + r)*64 + d] = (__bf16)(acc[i][j][r] + bv);
                } else {
                    const int h = (col - 1024) >> 6, d = col & 63;
                    bf16x4 pk;
                    #pragma unroll
                    for (int r = 0; r < 4; r++) pk[r] = (__bf16)(acc[i][j][r] + bv);
                    *(bf16x4*)&vtb[(((size_t)b*8 + h)*64 + d)*2048 + s0] = pk;
                }
            }
        }
    }
}

// ---------------- Flash attention with ALiBi --------------------------------
// grid (S/64, H, B), block 256 (4 waves, 16 q-rows each). 64-key tiles,
// double-buffered global_load_lds staging, exp2-based online softmax.
__global__ __launch_bounds__(256) void attn_kernel(
    const __bf16* __restrict__ qb, const __bf16* __restrict__ kb,
    const __bf16* __restrict__ vtb, __bf16* __restrict__ ctx)
{
    const int qt = blockIdx.x, h = blockIdx.y, b = blockIdx.z;
    const int bh = b * 8 + h;
    const int tid = threadIdx.x, wave = tid >> 6, lane = tid & 63;
    const int lrow = lane & 15, quad = lane >> 4;

    __shared__ __bf16 Ks[2][2][64 * 32];   // [buf][kh][key][32d]
    __shared__ __bf16 Vt[2][2][64 * 32];   // [buf][kh][d][32key]
    __shared__ __bf16 Pt[4][2][16 * 32];   // [wave][kh][q][32key]

    const float slope = -1.0f / (float)(h + 1);
    const float L2E = 1.44269504f;

    bf16x8 qf[2];
    {
        const int qrow = qt * 64 + wave * 16 + lrow;
        const __bf16* qp = qb + ((size_t)bh * 2048 + qrow) * 64 + quad * 8;
        qf[0] = *(const bf16x8*)qp;
        qf[1] = *(const bf16x8*)(qp + 32);
    }

    auto stage = [&](int kt, int buf) {
        const int rr = tid >> 2, c8 = (tid & 3) * 8;
        #pragma unroll
        for (int i = 0; i < 2; i++)
            gl_lds16(&kb[((size_t)bh * 2048 + kt * 64 + rr) * 64 + i * 32 + c8],
                     &Ks[buf][i][0] + tid * 8);
        #pragma unroll
        for (int i = 0; i < 2; i++)
            gl_lds16(&vtb[((size_t)bh * 64 + rr) * 2048 + kt * 64 + i * 32 + c8],
                     &Vt[buf][i][0] + tid * 8);
    };

    float m[4], l[4];
    f32x4 O[4] = {};
    #pragma unroll
    for (int r = 0; r < 4; r++) { m[r] = -1e30f; l[r] = 0.0f; }

    stage(0, 0);

    for (int kt = 0; kt < SEQ / 64; kt++) {
        __syncthreads();                       // staged buf visible; prior reads done
        if (kt + 1 < SEQ / 64) stage(kt + 1, (kt + 1) & 1);
        const int cur = kt & 1;

        // S = Q K^T : 4 col-tiles of 16 keys
        f32x4 Sc[4] = {};
        #pragma unroll
        for (int dh = 0; dh < 2; dh++) {
            #pragma unroll
            for (int j = 0; j < 4; j++) {
                bf16x8 kf = *(bf16x8*)&Ks[cur][dh][(j * 16 + lrow) * 32 + quad * 8];
                Sc[j] = __builtin_amdgcn_mfma_f32_16x16x32_bf16(qf[dh], kf, Sc[j], 0, 0, 0);
            }
        }

        // alibi + online softmax; P -> LDS (per-wave, no barrier)
        float alpha[4];
        #pragma unroll
        for (int r = 0; r < 4; r++) {
            const int qr = qt * 64 + wave * 16 + quad * 4 + r;
            float v[4], rowm = -1e30f;
            #pragma unroll
            for (int j = 0; j < 4; j++) {
                int kc = kt * 64 + j * 16 + lrow;
                v[j] = Sc[j][r] + slope * fabsf((float)(qr - kc));
                rowm = fmaxf(rowm, v[j]);
            }
            #pragma unroll
            for (int off = 1; off < 16; off <<= 1)
                rowm = fmaxf(rowm, __shfl_xor(rowm, off));
            float mn = fmaxf(m[r], rowm);
            alpha[r] = exp2f((m[r] - mn) * L2E);
            m[r] = mn;
            float rs = 0.0f;
            #pragma unroll
            for (int j = 0; j < 4; j++) {
                float p = exp2f((v[j] - mn) * L2E);
                rs += p;
                Pt[wave][j >> 1][(quad * 4 + r) * 32 + (j & 1) * 16 + lrow] = (__bf16)p;
            }
            #pragma unroll
            for (int off = 1; off < 16; off <<= 1)
                rs += __shfl_xor(rs, off);
            l[r] = l[r] * alpha[r] + rs;
        }

        // O = O*alpha + P V
        bf16x8 pf0 = *(bf16x8*)&Pt[wave][0][lrow * 32 + quad * 8];
        bf16x8 pf1 = *(bf16x8*)&Pt[wave][1][lrow * 32 + quad * 8];
        #pragma unroll
        for (int dt = 0; dt < 4; dt++) {
            #pragma unroll
            for (int r = 0; r < 4; r++) O[dt][r] *= alpha[r];
            bf16x8 vf0 = *(bf16x8*)&Vt[cur][0][(dt * 16 + lrow) * 32 + quad * 8];
            O[dt] = __builtin_amdgcn_mfma_f32_16x16x32_bf16(pf0, vf0, O[dt], 0, 0, 0);
            bf16x8 vf1 = *(bf16x8*)&Vt[cur][1][(dt * 16 + lrow) * 32 + quad * 8];
            O[dt] = __builtin_amdgcn_mfma_f32_16x16x32_bf16(pf1, vf1, O[dt], 0, 0, 0);
        }
    }

    #pragma unroll
    for (int dt = 0; dt < 4; dt++) {
        #pragma unroll
        for (int r = 0; r < 4; r++) {
            const int qr = qt * 64 + wave * 16 + quad * 4 + r;
            ctx[((size_t)(b * 2048 + qr)) * DMODEL + h * 64 + dt * 16 + lrow] =
                (__bf16)(O[dt][r] / l[r]);
        }
    }
}

// ---------------------------------------------------------------------------
extern "C" void kernel_launch(void* const* d_in, const int* in_sizes, int n_in,
                              void* d_out, int out_size, void* d_ws, size_t ws_size,
                              hipStream_t stream) {
    const float* x    = (const float*)d_in[0];
    const float* n1s  = (const float*)d_in[1];
    const float* n2s  = (const float*)d_in[2];
    const float* wqkv = (const float*)d_in[3];
    const float* bqkv = (const float*)d_in[4];
    const float* wout = (const float*)d_in[5];
    const float* bout = (const float*)d_in[6];
    const float* w1   = (const float*)d_in[7];
    const float* b1   = (const float*)d_in[8];
    const float* w2   = (const float*)d_in[9];
    const float* b2   = (const float*)d_in[10];
    float* out = (float*)d_out;

    char* ws = (char*)d_ws;
    __bf16* xn1    = (__bf16*)ws; ws += (size_t)TOKENS * DMODEL * 2;
    __bf16* qbuf   = (__bf16*)ws; ws += (size_t)TOKENS * DMODEL * 2;
    __bf16* kbuf   = (__bf16*)ws; ws += (size_t)TOKENS * DMODEL * 2;
    __bf16* vtbuf  = (__bf16*)ws; ws += (size_t)TOKENS * DMODEL * 2;
    __bf16* wqkv_b = (__bf16*)ws; ws += (size_t)1536 * DMODEL * 2;
    __bf16* wout_b = (__bf16*)ws; ws += (size_t)DMODEL * DMODEL * 2;
    __bf16* w1_b   = (__bf16*)ws; ws += (size_t)2048 * DMODEL * 2;
    __bf16* w2_b   = (__bf16*)ws; ws += (size_t)DMODEL * 2048 * 2;
    __bf16* ctx    = (__bf16*)ws; ws += (size_t)TOKENS * DMODEL * 2;
    float*  x1     = (float*)ws;  ws += (size_t)TOKENS * DMODEL * 4;
    __bf16* xn2    = (__bf16*)ws; ws += (size_t)TOKENS * DMODEL * 2;
    __bf16* hbuf   = (__bf16*)ws; ws += (size_t)TOKENS * 2048 * 2;

    cvt_f32_bf16<<<dim3(1536 * DMODEL / 1024), 256, 0, stream>>>(wqkv, wqkv_b, 1536 * DMODEL);
    cvt_f32_bf16<<<dim3(DMODEL * DMODEL / 1024), 256, 0, stream>>>(wout, wout_b, DMODEL * DMODEL);
    cvt_f32_bf16<<<dim3(2048 * DMODEL / 1024), 256, 0, stream>>>(w1, w1_b, 2048 * DMODEL);
    cvt_f32_bf16<<<dim3(DMODEL * 2048 / 1024), 256, 0, stream>>>(w2, w2_b, DMODEL * 2048);

    rmsnorm_kernel<<<dim3(TOKENS / 4), 256, 0, stream>>>(x, n1s, xn1);

    // qkv GEMM, epilogue splits into attention layouts (Q pre-scaled)
    gemm_bt<4, 64><<<dim3(TOKENS / 64, 1536 / 128), 256, 0, stream>>>(
        xn1, wqkv_b, bqkv, nullptr, nullptr, nullptr, qbuf, kbuf, vtbuf,
        TOKENS, 1536, DMODEL);

    attn_kernel<<<dim3(SEQ / 64, 8, 2), 256, 0, stream>>>(qbuf, kbuf, vtbuf, ctx);

    // x1 = x + ctx @ Wout^T + bias
    gemm_bt<1, 64><<<dim3(TOKENS / 64, DMODEL / 128), 256, 0, stream>>>(
        ctx, wout_b, bout, x, x1, nullptr, nullptr, nullptr, nullptr,
        TOKENS, DMODEL, DMODEL);

    rmsnorm_kernel<<<dim3(TOKENS / 4), 256, 0, stream>>>(x1, n2s, xn2);

    // h = gelu(xn2 @ W1^T + b1)
    gemm_bt<2, 128><<<dim3(TOKENS / 128, 2048 / 128), 256, 0, stream>>>(
        xn2, w1_b, b1, nullptr, nullptr, hbuf, nullptr, nullptr, nullptr,
        TOKENS, 2048, DMODEL);

    // out = x1 + h @ W2^T + b2
    gemm_bt<1, 64><<<dim3(TOKENS / 64, DMODEL / 128), 256, 0, stream>>>(
        hbuf, w2_b, b2, x1, out, nullptr, nullptr, nullptr, nullptr,
        TOKENS, DMODEL, 2048);
}

// Round 3
// 203.506 us; speedup vs baseline: 1.7089x; 1.2632x over previous
//
#include <hip/hip_runtime.h>
#include <math.h>

// ---------------------------------------------------------------------------
// TransformerBlock: B=2, S=2048, D=512, H=8, HD=64, DFF=2048, fp32 in/out.
// bf16 MFMA 16x16x32. Verified layouts:
//   A-frag:  A[m = lane&15][k = (lane>>4)*8 + j]
//   B-frag:  B[n = lane&15][k = (lane>>4)*8 + j]   (W[N][K] row-major)
//   C/D:     col = lane&15, row = (lane>>4)*4 + reg
// Attention: m=0 streaming softmax (scores bounded: |q.k|*scale <~ 2, alibi<=0)
//   => additive split-K flash; l via ones-MFMA; exp2-folded scales.
// V stored key-PERMUTED within 32-groups: position c' holds key g where
//   c' = 2*(g&15) + (g>>4). P-writes use the same perm => PV consistent.
// ---------------------------------------------------------------------------

typedef __bf16 bf16x8 __attribute__((ext_vector_type(8)));
typedef float  f32x4  __attribute__((ext_vector_type(4)));

#define TOKENS 4096
#define DMODEL 512
#define SEQ    2048
#define SPLITK 4
#define QSCALE 0.1803368801f   // 0.125 * log2(e)

__device__ __forceinline__ void gl_lds16(const __bf16* g, __bf16* l) {
    __builtin_amdgcn_global_load_lds(
        (const __attribute__((address_space(1))) void*)g,
        (__attribute__((address_space(3))) void*)l, 16, 0, 0);
}

union PkU { unsigned u; __bf16 h[2]; };

// ---------------- all 4 weight converts in one launch ----------------
__global__ void cvt_all(const float* __restrict__ w0, const float* __restrict__ w1,
                        const float* __restrict__ w2, const float* __restrict__ w3,
                        __bf16* __restrict__ d0, __bf16* __restrict__ d1,
                        __bf16* __restrict__ d2, __bf16* __restrict__ d3) {
    const int N0 = 1536 * 512, N1 = 512 * 512, N2 = 2048 * 512, N3 = 512 * 2048;
    int i4 = (blockIdx.x * 256 + threadIdx.x) * 4;
    const float* s; __bf16* d;
    if (i4 < N0)                   { s = w0 + i4;  d = d0 + i4; }
    else if ((i4 -= N0) < N1)      { s = w1 + i4;  d = d1 + i4; }
    else if ((i4 -= N1) < N2)      { s = w2 + i4;  d = d2 + i4; }
    else if ((i4 -= N2) < N3)      { s = w3 + i4;  d = d3 + i4; }
    else return;
    float4 v = *(const float4*)s;
    d[0] = (__bf16)v.x; d[1] = (__bf16)v.y; d[2] = (__bf16)v.z; d[3] = (__bf16)v.w;
}

// ---------------- RMSNorm: fp32 in -> bf16 out, one wave per token ----------
__global__ void rmsnorm_kernel(const float* __restrict__ x, const float* __restrict__ scale,
                               __bf16* __restrict__ out) {
    int wave = threadIdx.x >> 6, lane = threadIdx.x & 63;
    int tok = blockIdx.x * 4 + wave;
    const float* row = x + (size_t)tok * DMODEL;
    float4 v0 = *(const float4*)&row[lane * 4];
    float4 v1 = *(const float4*)&row[256 + lane * 4];
    float ss = v0.x*v0.x + v0.y*v0.y + v0.z*v0.z + v0.w*v0.w
             + v1.x*v1.x + v1.y*v1.y + v1.z*v1.z + v1.w*v1.w;
    #pragma unroll
    for (int off = 1; off < 64; off <<= 1) ss += __shfl_xor(ss, off);
    float r = rsqrtf(ss * (1.0f / DMODEL) + 1e-8f);
    __bf16* o = out + (size_t)tok * DMODEL;
    o[lane*4 + 0] = (__bf16)(v0.x * r * scale[lane*4 + 0]);
    o[lane*4 + 1] = (__bf16)(v0.y * r * scale[lane*4 + 1]);
    o[lane*4 + 2] = (__bf16)(v0.z * r * scale[lane*4 + 2]);
    o[lane*4 + 3] = (__bf16)(v0.w * r * scale[lane*4 + 3]);
    o[256 + lane*4 + 0] = (__bf16)(v1.x * r * scale[256 + lane*4 + 0]);
    o[256 + lane*4 + 1] = (__bf16)(v1.y * r * scale[256 + lane*4 + 1]);
    o[256 + lane*4 + 2] = (__bf16)(v1.z * r * scale[256 + lane*4 + 2]);
    o[256 + lane*4 + 3] = (__bf16)(v1.w * r * scale[256 + lane*4 + 3]);
}

// ---------------- GEMM: C[M,N] = A[M,K] @ W[N,K]^T + bias ------------------
// EPI: 1 = fp32 res + C + bias
//      2 = bf16 gelu(C+bias)
//      4 = qkv split: Q*QSCALE -> qb[b,h,s,d], K -> kb[b,h,s,d],
//          V -> vtb[b,h,d,s'] with s' key-permuted in 32-groups (packed b32)
template <int EPI, int TM>
__global__ __launch_bounds__(256) void gemm_bt(
    const __bf16* __restrict__ A, const __bf16* __restrict__ W,
    const float* __restrict__ bias, const float* __restrict__ res,
    float* __restrict__ Cf, __bf16* __restrict__ Cb,
    __bf16* __restrict__ qb, __bf16* __restrict__ kb, __bf16* __restrict__ vtb,
    int M, int N, int K)
{
    constexpr int RI = TM / 32;
    __shared__ alignas(16) __bf16 As[2][TM * 32];
    __shared__ alignas(16) __bf16 Bs[2][128 * 32];
    const int tid = threadIdx.x;
    const int bm = blockIdx.x * TM;
    const int bn = blockIdx.y * 128;
    const int wave = tid >> 6, lane = tid & 63;
    const int wm = (wave & 1) * (TM / 2), wn = (wave >> 1) * 64;
    const int lrow = lane & 15;
    const int kq = (lane >> 4) * 8;

    f32x4 acc[RI][4] = {};

    for (int k0 = 0; k0 < K; k0 += 64) {
        __syncthreads();
        #pragma unroll
        for (int i = 0; i < TM / 32; i++) {
            int tt = i * 256 + tid;
            int kh = tt / (TM * 4), rem = tt % (TM * 4);
            int mrow = rem >> 2, c8 = rem & 3;
            gl_lds16(&A[(size_t)(bm + mrow) * K + k0 + kh * 32 + c8 * 8],
                     (__bf16*)As + tt * 8);
        }
        #pragma unroll
        for (int i = 0; i < 4; i++) {
            int tt = i * 256 + tid;
            int kh = tt >> 9, rem = tt & 511;
            int nrow = rem >> 2, c8 = rem & 3;
            gl_lds16(&W[(size_t)(bn + nrow) * K + k0 + kh * 32 + c8 * 8],
                     (__bf16*)Bs + tt * 8);
        }
        __syncthreads();
        #pragma unroll
        for (int kh = 0; kh < 2; kh++) {
            bf16x8 af[RI], bfv[4];
            #pragma unroll
            for (int i = 0; i < RI; i++) af[i] = *(bf16x8*)&As[kh][(wm + i*16 + lrow)*32 + kq];
            #pragma unroll
            for (int j = 0; j < 4; j++) bfv[j] = *(bf16x8*)&Bs[kh][(wn + j*16 + lrow)*32 + kq];
            #pragma unroll
            for (int i = 0; i < RI; i++)
                #pragma unroll
                for (int j = 0; j < 4; j++)
                    acc[i][j] = __builtin_amdgcn_mfma_f32_16x16x32_bf16(af[i], bfv[j], acc[i][j], 0, 0, 0);
        }
    }

    const int crow0 = (lane >> 4) * 4;
    const int ccol = lane & 15;
    const int quad = lane >> 4;

    if (EPI == 4) {   // TM == 64 assumed (RI == 2)
        #pragma unroll
        for (int j = 0; j < 4; j++) {
            const int col = bn + wn + j * 16 + ccol;
            const float bv = bias[col];
            if (col < 512) {
                const int h = col >> 6, d = col & 63;
                #pragma unroll
                for (int i = 0; i < RI; i++) {
                    const int row0 = bm + wm + i * 16 + crow0;
                    const int b = row0 >> 11, s0 = row0 & 2047;
                    #pragma unroll
                    for (int r = 0; r < 4; r++)
                        qb[(((size_t)b*8 + h)*2048 + s0 + r)*64 + d] =
                            (__bf16)((acc[i][j][r] + bv) * QSCALE);
                }
            } else if (col < 1024) {
                const int h = (col - 512) >> 6, d = col & 63;
                #pragma unroll
                for (int i = 0; i < RI; i++) {
                    const int row0 = bm + wm + i * 16 + crow0;
                    const int b = row0 >> 11, s0 = row0 & 2047;
                    #pragma unroll
                    for (int r = 0; r < 4; r++)
                        kb[(((size_t)b*8 + h)*2048 + s0 + r)*64 + d] = (__bf16)(acc[i][j][r] + bv);
                }
            } else {
                const int h = (col - 1024) >> 6, d = col & 63;
                const int tok0 = bm + wm;            // 32-aligned, no batch straddle
                const int b = tok0 >> 11, sbase = tok0 & 2047;
                unsigned* vrow = (unsigned*)vtb + (((size_t)b*8 + h)*64 + d) * 1024 + (sbase >> 1);
                #pragma unroll
                for (int r = 0; r < 4; r++) {
                    PkU pk;                          // c' = 2*(g&15) + i  (g = quad*4+r)
                    pk.h[0] = (__bf16)(acc[0][j][r] + bv);
                    pk.h[1] = (__bf16)(acc[1][j][r] + bv);
                    vrow[quad * 4 + r] = pk.u;
                }
            }
        }
    } else {
        #pragma unroll
        for (int i = 0; i < RI; i++) {
            const int row0 = bm + wm + i * 16 + crow0;
            #pragma unroll
            for (int j = 0; j < 4; j++) {
                const int col = bn + wn + j * 16 + ccol;
                const float bv = bias[col];
                if (EPI == 1) {
                    #pragma unroll
                    for (int r = 0; r < 4; r++) {
                        const size_t idx = (size_t)(row0 + r) * N + col;
                        Cf[idx] = res[idx] + acc[i][j][r] + bv;
                    }
                } else { // EPI == 2
                    #pragma unroll
                    for (int r = 0; r < 4; r++) {
                        float v = acc[i][j][r] + bv;
                        Cb[(size_t)(row0 + r) * N + col] =
                            (__bf16)(0.5f * v * (1.0f + erff(v * 0.70710678f)));
                    }
                }
            }
        }
    }
}

// ---------------- Flash attention, m=0 streaming, split-K -------------------
// grid (S/128, B*H, SPLITK), block 256 = 4 waves x 32 q-rows.
// Q pre-scaled by 0.125*log2e; p = exp2(Sc + slope2*|dq-dk|).
__global__ __launch_bounds__(256, 4) void attn_kernel(
    const __bf16* __restrict__ qb, const __bf16* __restrict__ kb,
    const __bf16* __restrict__ vtb,
    float* __restrict__ Opart, float* __restrict__ lpart)
{
    const int qt = blockIdx.x, bh = blockIdx.y, sp = blockIdx.z;
    const int h = bh & 7;
    const int tid = threadIdx.x, wave = tid >> 6, lane = tid & 63;
    const int lrow = lane & 15, quad = lane >> 4;

    __shared__ alignas(16) __bf16 Ks[2][64 * 32];        // [d-half][key][32d]
    __shared__ alignas(16) __bf16 Vt[2][64 * 32];        // [key-half][d][32key'] (permuted)
    __shared__ alignas(16) unsigned Pt4[4][2][32][20];   // [wave][key-half][q][pairs(+pad)]

    const float slope2 = -1.44269504f / (float)(h + 1);
    const int qbase = qt * 128 + wave * 32;

    bf16x8 qf[2][2];
    #pragma unroll
    for (int rt = 0; rt < 2; rt++)
        #pragma unroll
        for (int dh = 0; dh < 2; dh++)
            qf[rt][dh] = *(const bf16x8*)&qb[((size_t)bh*2048 + qbase + rt*16 + lrow)*64 + dh*32 + quad*8];

    bf16x8 ones;
    #pragma unroll
    for (int j = 0; j < 8; j++) ones[j] = (__bf16)1.0f;

    f32x4 O[2][4] = {};
    f32x4 lacc[2] = {};

    for (int kt = sp * (32 / SPLITK); kt < (sp + 1) * (32 / SPLITK); kt++) {
        const int kbase = kt * 64;
        __syncthreads();                      // prior tile's LDS reads done
        {   // stage K and V' (2 + 2 gl_lds16 per thread)
            #pragma unroll
            for (int i = 0; i < 2; i++) {
                int tt = i * 256 + tid;
                int dh = tt >> 8, key = (tt & 255) >> 2, c8 = (tt & 3) * 8;
                gl_lds16(&kb[((size_t)bh*2048 + kbase + key)*64 + dh*32 + c8],
                         (__bf16*)Ks + tt * 8);
            }
            #pragma unroll
            for (int i = 0; i < 2; i++) {
                int tt = i * 256 + tid;
                int kh = tt >> 8, d = (tt & 255) >> 2, ck = (tt & 3) * 8;
                gl_lds16(&vtb[((size_t)bh*64 + d)*2048 + kbase + kh*32 + ck],
                         (__bf16*)Vt + tt * 8);
            }
        }
        __syncthreads();                      // staging visible

        bf16x8 kf[4][2];
        #pragma unroll
        for (int j = 0; j < 4; j++)
            #pragma unroll
            for (int dh = 0; dh < 2; dh++)
                kf[j][dh] = *(bf16x8*)&Ks[dh][(j*16 + lrow)*32 + quad*8];

        #pragma unroll
        for (int rt = 0; rt < 2; rt++) {
            f32x4 Sc[4] = {};
            #pragma unroll
            for (int dh = 0; dh < 2; dh++)
                #pragma unroll
                for (int j = 0; j < 4; j++)
                    Sc[j] = __builtin_amdgcn_mfma_f32_16x16x32_bf16(qf[rt][dh], kf[j][dh], Sc[j], 0, 0, 0);

            const float dbase = (float)(qbase + rt*16 + quad*4 - kbase - lrow);
            #pragma unroll
            for (int r = 0; r < 4; r++) {
                const float d0 = dbase + (float)r;
                #pragma unroll
                for (int jp = 0; jp < 2; jp++) {
                    float v0 = fmaf(slope2, fabsf(d0 - (float)(jp*32)),      Sc[2*jp  ][r]);
                    float v1 = fmaf(slope2, fabsf(d0 - (float)(jp*32 + 16)), Sc[2*jp+1][r]);
                    PkU pk;
                    pk.h[0] = (__bf16)exp2f(v0);   // c' = 2*lrow
                    pk.h[1] = (__bf16)exp2f(v1);   // c' = 2*lrow+1
                    Pt4[wave][jp][rt*16 + quad*4 + r][lrow] = pk.u;
                }
            }
        }

        bf16x8 pf[2][2];
        #pragma unroll
        for (int rt = 0; rt < 2; rt++)
            #pragma unroll
            for (int kh = 0; kh < 2; kh++)
                pf[rt][kh] = *(bf16x8*)&Pt4[wave][kh][rt*16 + lrow][quad*4];

        #pragma unroll
        for (int rt = 0; rt < 2; rt++)
            #pragma unroll
            for (int kh = 0; kh < 2; kh++)
                lacc[rt] = __builtin_amdgcn_mfma_f32_16x16x32_bf16(pf[rt][kh], ones, lacc[rt], 0, 0, 0);

        #pragma unroll
        for (int dt = 0; dt < 4; dt++) {
            #pragma unroll
            for (int kh = 0; kh < 2; kh++) {
                bf16x8 vf = *(bf16x8*)&Vt[kh][(dt*16 + lrow)*32 + quad*8];
                #pragma unroll
                for (int rt = 0; rt < 2; rt++)
                    O[rt][dt] = __builtin_amdgcn_mfma_f32_16x16x32_bf16(pf[rt][kh], vf, O[rt][dt], 0, 0, 0);
            }
        }
    }

    // write partials (raw O and l; combine kernel divides)
    #pragma unroll
    for (int rt = 0; rt < 2; rt++) {
        #pragma unroll
        for (int dt = 0; dt < 4; dt++)
            #pragma unroll
            for (int r = 0; r < 4; r++) {
                const int q = qbase + rt*16 + quad*4 + r;
                Opart[(((size_t)sp*16 + bh)*2048 + q)*64 + dt*16 + lrow] = O[rt][dt][r];
            }
        if (lrow == 0) {
            #pragma unroll
            for (int r = 0; r < 4; r++)
                lpart[((size_t)sp*16 + bh)*2048 + qbase + rt*16 + quad*4 + r] = lacc[rt][r];
        }
    }
}

// ---------------- combine split-K partials -> ctx bf16 ----------------------
__global__ void combine_kernel(const float* __restrict__ Opart, const float* __restrict__ lpart,
                               __bf16* __restrict__ ctx) {
    const int idx = blockIdx.x * 256 + threadIdx.x;   // 16*2048*32 threads
    const int d2 = idx & 31;
    const int q  = (idx >> 5) & 2047;
    const int bh = idx >> 16;
    float ox = 0.0f, oy = 0.0f, l = 0.0f;
    #pragma unroll
    for (int sp = 0; sp < SPLITK; sp++) {
        const float2 o = *(const float2*)&Opart[(((size_t)sp*16 + bh)*2048 + q)*64 + d2*2];
        ox += o.x; oy += o.y;
        l += lpart[((size_t)sp*16 + bh)*2048 + q];
    }
    const float inv = 1.0f / l;
    PkU pk;
    pk.h[0] = (__bf16)(ox * inv);
    pk.h[1] = (__bf16)(oy * inv);
    const int b = bh >> 3, h = bh & 7;
    *((unsigned*)ctx + (((size_t)b*2048 + q)*512 + h*64) / 2 + d2) = pk.u;
}

// ---------------------------------------------------------------------------
extern "C" void kernel_launch(void* const* d_in, const int* in_sizes, int n_in,
                              void* d_out, int out_size, void* d_ws, size_t ws_size,
                              hipStream_t stream) {
    const float* x    = (const float*)d_in[0];
    const float* n1s  = (const float*)d_in[1];
    const float* n2s  = (const float*)d_in[2];
    const float* wqkv = (const float*)d_in[3];
    const float* bqkv = (const float*)d_in[4];
    const float* wout = (const float*)d_in[5];
    const float* bout = (const float*)d_in[6];
    const float* w1   = (const float*)d_in[7];
    const float* b1   = (const float*)d_in[8];
    const float* w2   = (const float*)d_in[9];
    const float* b2   = (const float*)d_in[10];
    float* out = (float*)d_out;

    char* ws = (char*)d_ws;
    __bf16* xn1    = (__bf16*)ws; ws += (size_t)TOKENS * DMODEL * 2;
    __bf16* qbuf   = (__bf16*)ws; ws += (size_t)TOKENS * DMODEL * 2;
    __bf16* kbuf   = (__bf16*)ws; ws += (size_t)TOKENS * DMODEL * 2;
    __bf16* vtbuf  = (__bf16*)ws; ws += (size_t)TOKENS * DMODEL * 2;
    __bf16* wqkv_b = (__bf16*)ws; ws += (size_t)1536 * DMODEL * 2;
    __bf16* wout_b = (__bf16*)ws; ws += (size_t)DMODEL * DMODEL * 2;
    __bf16* w1_b   = (__bf16*)ws; ws += (size_t)2048 * DMODEL * 2;
    __bf16* w2_b   = (__bf16*)ws; ws += (size_t)DMODEL * 2048 * 2;
    __bf16* ctx    = (__bf16*)ws; ws += (size_t)TOKENS * DMODEL * 2;
    float*  lpart  = (float*)ws;  ws += (size_t)SPLITK * 16 * 2048 * 4;
    // shared region: Opart (dead after combine) overlaps x1/xn2/hbuf
    float*  Opart  = (float*)ws;                       // SPLITK*16*2048*64*4 = 33.5 MB
    float*  x1     = (float*)ws;  ws += (size_t)TOKENS * DMODEL * 4;
    __bf16* xn2    = (__bf16*)ws; ws += (size_t)TOKENS * DMODEL * 2;
    __bf16* hbuf   = (__bf16*)ws;

    cvt_all<<<dim3(3072), 256, 0, stream>>>(wqkv, wout, w1, w2, wqkv_b, wout_b, w1_b, w2_b);

    rmsnorm_kernel<<<dim3(TOKENS / 4), 256, 0, stream>>>(x, n1s, xn1);

    // qkv GEMM, epilogue -> q (scaled), k, v-transposed-permuted
    gemm_bt<4, 64><<<dim3(TOKENS / 64, 1536 / 128), 256, 0, stream>>>(
        xn1, wqkv_b, bqkv, nullptr, nullptr, nullptr, qbuf, kbuf, vtbuf,
        TOKENS, 1536, DMODEL);

    attn_kernel<<<dim3(SEQ / 128, 16, SPLITK), 256, 0, stream>>>(
        qbuf, kbuf, vtbuf, Opart, lpart);

    combine_kernel<<<dim3(16 * 2048 * 32 / 256), 256, 0, stream>>>(Opart, lpart, ctx);

    // x1 = x + ctx @ Wout^T + bias
    gemm_bt<1, 32><<<dim3(TOKENS / 32, DMODEL / 128), 256, 0, stream>>>(
        ctx, wout_b, bout, x, x1, nullptr, nullptr, nullptr, nullptr,
        TOKENS, DMODEL, DMODEL);

    rmsnorm_kernel<<<dim3(TOKENS / 4), 256, 0, stream>>>(x1, n2s, xn2);

    // h = gelu(xn2 @ W1^T + b1)
    gemm_bt<2, 128><<<dim3(TOKENS / 128, 2048 / 128), 256, 0, stream>>>(
        xn2, w1_b, b1, nullptr, nullptr, hbuf, nullptr, nullptr, nullptr,
        TOKENS, 2048, DMODEL);

    // out = x1 + h @ W2^T + b2
    gemm_bt<1, 32><<<dim3(TOKENS / 32, DMODEL / 128), 256, 0, stream>>>(
        hbuf, w2_b, b2, x1, out, nullptr, nullptr, nullptr, nullptr,
        TOKENS, DMODEL, 2048);
}

// Round 4
// 200.815 us; speedup vs baseline: 1.7318x; 1.0134x over previous
//
#include <hip/hip_runtime.h>
#include <math.h>

// ---------------------------------------------------------------------------
// TransformerBlock: B=2, S=2048, D=512, H=8, HD=64, DFF=2048, fp32 in/out.
// bf16 MFMA 16x16x32. Verified layouts:
//   A-frag:  A[m = lane&15][k = (lane>>4)*8 + j]
//   B-frag:  B[n = lane&15][k = (lane>>4)*8 + j]   (W[N][K] row-major)
//   C/D:     col = lane&15, row = (lane>>4)*4 + reg
// Attention: m=0 streaming softmax (scores bounded), split-K=2, l via
// ones-MFMA, bf16 partials, double-buffered global_load_lds staging.
// V stored key-permuted in 32-groups: c' = 2*(g&15) + (g>>4).
// ---------------------------------------------------------------------------

typedef __bf16 bf16x8 __attribute__((ext_vector_type(8)));
typedef float  f32x4  __attribute__((ext_vector_type(4)));

#define TOKENS 4096
#define DMODEL 512
#define SEQ    2048
#define SPLITK 2
#define QSCALE 0.1803368801f   // 0.125 * log2(e)

__device__ __forceinline__ void gl_lds16(const __bf16* g, __bf16* l) {
    __builtin_amdgcn_global_load_lds(
        (const __attribute__((address_space(1))) void*)g,
        (__attribute__((address_space(3))) void*)l, 16, 0, 0);
}

union PkU { unsigned u; __bf16 h[2]; };

// ------- fused: rmsnorm1 (blocks 0..1023) + 4 weight converts (1024..4095) --
__global__ void pre_kernel(const float* __restrict__ x, const float* __restrict__ n1s,
                           __bf16* __restrict__ xn1,
                           const float* __restrict__ w0, const float* __restrict__ w1,
                           const float* __restrict__ w2, const float* __restrict__ w3,
                           __bf16* __restrict__ d0, __bf16* __restrict__ d1,
                           __bf16* __restrict__ d2, __bf16* __restrict__ d3) {
    if (blockIdx.x < 1024) {
        int wave = threadIdx.x >> 6, lane = threadIdx.x & 63;
        int tok = blockIdx.x * 4 + wave;
        const float* row = x + (size_t)tok * DMODEL;
        float4 v0 = *(const float4*)&row[lane * 4];
        float4 v1 = *(const float4*)&row[256 + lane * 4];
        float ss = v0.x*v0.x + v0.y*v0.y + v0.z*v0.z + v0.w*v0.w
                 + v1.x*v1.x + v1.y*v1.y + v1.z*v1.z + v1.w*v1.w;
        #pragma unroll
        for (int off = 1; off < 64; off <<= 1) ss += __shfl_xor(ss, off);
        float r = rsqrtf(ss * (1.0f / DMODEL) + 1e-8f);
        __bf16* o = xn1 + (size_t)tok * DMODEL;
        o[lane*4 + 0] = (__bf16)(v0.x * r * n1s[lane*4 + 0]);
        o[lane*4 + 1] = (__bf16)(v0.y * r * n1s[lane*4 + 1]);
        o[lane*4 + 2] = (__bf16)(v0.z * r * n1s[lane*4 + 2]);
        o[lane*4 + 3] = (__bf16)(v0.w * r * n1s[lane*4 + 3]);
        o[256 + lane*4 + 0] = (__bf16)(v1.x * r * n1s[256 + lane*4 + 0]);
        o[256 + lane*4 + 1] = (__bf16)(v1.y * r * n1s[256 + lane*4 + 1]);
        o[256 + lane*4 + 2] = (__bf16)(v1.z * r * n1s[256 + lane*4 + 2]);
        o[256 + lane*4 + 3] = (__bf16)(v1.w * r * n1s[256 + lane*4 + 3]);
    } else {
        const int N0 = 1536 * 512, N1 = 512 * 512, N2 = 2048 * 512, N3 = 512 * 2048;
        int i4 = ((blockIdx.x - 1024) * 256 + threadIdx.x) * 4;
        const float* s; __bf16* d;
        if (i4 < N0)              { s = w0 + i4;  d = d0 + i4; }
        else if ((i4 -= N0) < N1) { s = w1 + i4;  d = d1 + i4; }
        else if ((i4 -= N1) < N2) { s = w2 + i4;  d = d2 + i4; }
        else if ((i4 -= N2) < N3) { s = w3 + i4;  d = d3 + i4; }
        else return;
        float4 v = *(const float4*)s;
        d[0] = (__bf16)v.x; d[1] = (__bf16)v.y; d[2] = (__bf16)v.z; d[3] = (__bf16)v.w;
    }
}

// ---------------- RMSNorm standalone (norm2) --------------------------------
__global__ void rmsnorm_kernel(const float* __restrict__ x, const float* __restrict__ scale,
                               __bf16* __restrict__ out) {
    int wave = threadIdx.x >> 6, lane = threadIdx.x & 63;
    int tok = blockIdx.x * 4 + wave;
    const float* row = x + (size_t)tok * DMODEL;
    float4 v0 = *(const float4*)&row[lane * 4];
    float4 v1 = *(const float4*)&row[256 + lane * 4];
    float ss = v0.x*v0.x + v0.y*v0.y + v0.z*v0.z + v0.w*v0.w
             + v1.x*v1.x + v1.y*v1.y + v1.z*v1.z + v1.w*v1.w;
    #pragma unroll
    for (int off = 1; off < 64; off <<= 1) ss += __shfl_xor(ss, off);
    float r = rsqrtf(ss * (1.0f / DMODEL) + 1e-8f);
    __bf16* o = out + (size_t)tok * DMODEL;
    o[lane*4 + 0] = (__bf16)(v0.x * r * scale[lane*4 + 0]);
    o[lane*4 + 1] = (__bf16)(v0.y * r * scale[lane*4 + 1]);
    o[lane*4 + 2] = (__bf16)(v0.z * r * scale[lane*4 + 2]);
    o[lane*4 + 3] = (__bf16)(v0.w * r * scale[lane*4 + 3]);
    o[256 + lane*4 + 0] = (__bf16)(v1.x * r * scale[256 + lane*4 + 0]);
    o[256 + lane*4 + 1] = (__bf16)(v1.y * r * scale[256 + lane*4 + 1]);
    o[256 + lane*4 + 2] = (__bf16)(v1.z * r * scale[256 + lane*4 + 2]);
    o[256 + lane*4 + 3] = (__bf16)(v1.w * r * scale[256 + lane*4 + 3]);
}

// ---------------- GEMM: C[M,N] = A[M,K] @ W[N,K]^T + bias ------------------
// EPI: 1 = fp32 res + C + bias
//      2 = bf16 gelu(C+bias)
//      4 = qkv split: Q*QSCALE -> qb, K -> kb, V -> vtb (key-permuted pack)
template <int EPI, int TM>
__global__ __launch_bounds__(256) void gemm_bt(
    const __bf16* __restrict__ A, const __bf16* __restrict__ W,
    const float* __restrict__ bias, const float* __restrict__ res,
    float* __restrict__ Cf, __bf16* __restrict__ Cb,
    __bf16* __restrict__ qb, __bf16* __restrict__ kb, __bf16* __restrict__ vtb,
    int M, int N, int K)
{
    constexpr int RI = TM / 32;
    __shared__ alignas(16) __bf16 As[2][TM * 32];
    __shared__ alignas(16) __bf16 Bs[2][128 * 32];
    const int tid = threadIdx.x;
    const int bm = blockIdx.x * TM;
    const int bn = blockIdx.y * 128;
    const int wave = tid >> 6, lane = tid & 63;
    const int wm = (wave & 1) * (TM / 2), wn = (wave >> 1) * 64;
    const int lrow = lane & 15;
    const int kq = (lane >> 4) * 8;

    f32x4 acc[RI][4] = {};

    for (int k0 = 0; k0 < K; k0 += 64) {
        __syncthreads();
        #pragma unroll
        for (int i = 0; i < TM / 32; i++) {
            int tt = i * 256 + tid;
            int kh = tt / (TM * 4), rem = tt % (TM * 4);
            int mrow = rem >> 2, c8 = rem & 3;
            gl_lds16(&A[(size_t)(bm + mrow) * K + k0 + kh * 32 + c8 * 8],
                     (__bf16*)As + tt * 8);
        }
        #pragma unroll
        for (int i = 0; i < 4; i++) {
            int tt = i * 256 + tid;
            int kh = tt >> 9, rem = tt & 511;
            int nrow = rem >> 2, c8 = rem & 3;
            gl_lds16(&W[(size_t)(bn + nrow) * K + k0 + kh * 32 + c8 * 8],
                     (__bf16*)Bs + tt * 8);
        }
        __syncthreads();
        #pragma unroll
        for (int kh = 0; kh < 2; kh++) {
            bf16x8 af[RI], bfv[4];
            #pragma unroll
            for (int i = 0; i < RI; i++) af[i] = *(bf16x8*)&As[kh][(wm + i*16 + lrow)*32 + kq];
            #pragma unroll
            for (int j = 0; j < 4; j++) bfv[j] = *(bf16x8*)&Bs[kh][(wn + j*16 + lrow)*32 + kq];
            #pragma unroll
            for (int i = 0; i < RI; i++)
                #pragma unroll
                for (int j = 0; j < 4; j++)
                    acc[i][j] = __builtin_amdgcn_mfma_f32_16x16x32_bf16(af[i], bfv[j], acc[i][j], 0, 0, 0);
        }
    }

    const int crow0 = (lane >> 4) * 4;
    const int ccol = lane & 15;
    const int quad = lane >> 4;

    if (EPI == 4) {
        #pragma unroll
        for (int j = 0; j < 4; j++) {
            const int col = bn + wn + j * 16 + ccol;
            const float bv = bias[col];
            if (col < 512) {
                const int h = col >> 6, d = col & 63;
                #pragma unroll
                for (int i = 0; i < RI; i++) {
                    const int row0 = bm + wm + i * 16 + crow0;
                    const int b = row0 >> 11, s0 = row0 & 2047;
                    #pragma unroll
                    for (int r = 0; r < 4; r++)
                        qb[(((size_t)b*8 + h)*2048 + s0 + r)*64 + d] =
                            (__bf16)((acc[i][j][r] + bv) * QSCALE);
                }
            } else if (col < 1024) {
                const int h = (col - 512) >> 6, d = col & 63;
                #pragma unroll
                for (int i = 0; i < RI; i++) {
                    const int row0 = bm + wm + i * 16 + crow0;
                    const int b = row0 >> 11, s0 = row0 & 2047;
                    #pragma unroll
                    for (int r = 0; r < 4; r++)
                        kb[(((size_t)b*8 + h)*2048 + s0 + r)*64 + d] = (__bf16)(acc[i][j][r] + bv);
                }
            } else {
                const int h = (col - 1024) >> 6, d = col & 63;
                const int tok0 = bm + wm;            // 32-aligned, no batch straddle
                const int b = tok0 >> 11, sbase = tok0 & 2047;
                unsigned* vrow = (unsigned*)vtb + (((size_t)b*8 + h)*64 + d) * 1024 + (sbase >> 1);
                #pragma unroll
                for (int ip = 0; ip < RI / 2; ip++) {   // 32-token groups
                    #pragma unroll
                    for (int r = 0; r < 4; r++) {
                        PkU pk;                          // c' = 2*(g&15) + (g>>4)
                        pk.h[0] = (__bf16)(acc[2*ip][j][r] + bv);
                        pk.h[1] = (__bf16)(acc[2*ip+1][j][r] + bv);
                        vrow[ip * 16 + quad * 4 + r] = pk.u;
                    }
                }
            }
        }
    } else {
        #pragma unroll
        for (int i = 0; i < RI; i++) {
            const int row0 = bm + wm + i * 16 + crow0;
            #pragma unroll
            for (int j = 0; j < 4; j++) {
                const int col = bn + wn + j * 16 + ccol;
                const float bv = bias[col];
                if (EPI == 1) {
                    #pragma unroll
                    for (int r = 0; r < 4; r++) {
                        const size_t idx = (size_t)(row0 + r) * N + col;
                        Cf[idx] = res[idx] + acc[i][j][r] + bv;
                    }
                } else { // EPI == 2
                    #pragma unroll
                    for (int r = 0; r < 4; r++) {
                        float v = acc[i][j][r] + bv;
                        Cb[(size_t)(row0 + r) * N + col] =
                            (__bf16)(0.5f * v * (1.0f + erff(v * 0.70710678f)));
                    }
                }
            }
        }
    }
}

// ---------------- Flash attention, m=0 streaming, split-K=2 -----------------
// grid (S/128, B*H, SPLITK), block 256 = 4 waves x 32 q-rows.
// Double-buffered K/V staging: one barrier per 64-key tile.
__global__ __launch_bounds__(256, 4) void attn_kernel(
    const __bf16* __restrict__ qb, const __bf16* __restrict__ kb,
    const __bf16* __restrict__ vtb,
    __bf16* __restrict__ Opart, float* __restrict__ lpart)
{
    const int qt = blockIdx.x, bh = blockIdx.y, sp = blockIdx.z;
    const int h = bh & 7;
    const int tid = threadIdx.x, wave = tid >> 6, lane = tid & 63;
    const int lrow = lane & 15, quad = lane >> 4;

    __shared__ alignas(16) __bf16 Ks[2][2][64 * 32];     // [buf][d-half][key][32d]
    __shared__ alignas(16) __bf16 Vt[2][2][64 * 32];     // [buf][key-half][d][32key']
    __shared__ alignas(16) unsigned Pt4[4][2][32][20];   // [wave][key-half][q][pairs+pad]

    const float slope2 = -1.44269504f / (float)(h + 1);
    const int qbase = qt * 128 + wave * 32;
    const int kt0 = sp * (32 / SPLITK), kt1 = kt0 + 32 / SPLITK;

    bf16x8 qf[2][2];
    #pragma unroll
    for (int rt = 0; rt < 2; rt++)
        #pragma unroll
        for (int dh = 0; dh < 2; dh++)
            qf[rt][dh] = *(const bf16x8*)&qb[((size_t)bh*2048 + qbase + rt*16 + lrow)*64 + dh*32 + quad*8];

    bf16x8 ones;
    #pragma unroll
    for (int j = 0; j < 8; j++) ones[j] = (__bf16)1.0f;

    f32x4 O[2][4] = {};
    f32x4 lacc[2] = {};

    auto stage = [&](int kt, int buf) {
        const int kbase = kt * 64;
        #pragma unroll
        for (int i = 0; i < 2; i++) {
            int tt = i * 256 + tid;
            int dh = tt >> 8, key = (tt & 255) >> 2, c8 = (tt & 3) * 8;
            gl_lds16(&kb[((size_t)bh*2048 + kbase + key)*64 + dh*32 + c8],
                     (__bf16*)Ks[buf] + tt * 8);
        }
        #pragma unroll
        for (int i = 0; i < 2; i++) {
            int tt = i * 256 + tid;
            int kh = tt >> 8, d = (tt & 255) >> 2, ck = (tt & 3) * 8;
            gl_lds16(&vtb[((size_t)bh*64 + d)*2048 + kbase + kh*32 + ck],
                     (__bf16*)Vt[buf] + tt * 8);
        }
    };

    stage(kt0, 0);

    for (int kt = kt0, buf = 0; kt < kt1; kt++, buf ^= 1) {
        const int kbase = kt * 64;
        __syncthreads();                          // staged buf ready; old reads done
        if (kt + 1 < kt1) stage(kt + 1, buf ^ 1);

        bf16x8 kf[4][2];
        #pragma unroll
        for (int j = 0; j < 4; j++)
            #pragma unroll
            for (int dh = 0; dh < 2; dh++)
                kf[j][dh] = *(bf16x8*)&Ks[buf][dh][(j*16 + lrow)*32 + quad*8];

        #pragma unroll
        for (int rt = 0; rt < 2; rt++) {
            f32x4 Sc[4] = {};
            #pragma unroll
            for (int dh = 0; dh < 2; dh++)
                #pragma unroll
                for (int j = 0; j < 4; j++)
                    Sc[j] = __builtin_amdgcn_mfma_f32_16x16x32_bf16(qf[rt][dh], kf[j][dh], Sc[j], 0, 0, 0);

            const float dbase = (float)(qbase + rt*16 + quad*4 - kbase - lrow);
            #pragma unroll
            for (int r = 0; r < 4; r++) {
                const float d0 = dbase + (float)r;
                #pragma unroll
                for (int jp = 0; jp < 2; jp++) {
                    float v0 = fmaf(slope2, fabsf(d0 - (float)(jp*32)),      Sc[2*jp  ][r]);
                    float v1 = fmaf(slope2, fabsf(d0 - (float)(jp*32 + 16)), Sc[2*jp+1][r]);
                    PkU pk;
                    pk.h[0] = (__bf16)exp2f(v0);
                    pk.h[1] = (__bf16)exp2f(v1);
                    Pt4[wave][jp][rt*16 + quad*4 + r][lrow] = pk.u;
                }
            }
        }

        bf16x8 pf[2][2];
        #pragma unroll
        for (int rt = 0; rt < 2; rt++)
            #pragma unroll
            for (int kh = 0; kh < 2; kh++)
                pf[rt][kh] = *(bf16x8*)&Pt4[wave][kh][rt*16 + lrow][quad*4];

        #pragma unroll
        for (int rt = 0; rt < 2; rt++)
            #pragma unroll
            for (int kh = 0; kh < 2; kh++)
                lacc[rt] = __builtin_amdgcn_mfma_f32_16x16x32_bf16(pf[rt][kh], ones, lacc[rt], 0, 0, 0);

        #pragma unroll
        for (int dt = 0; dt < 4; dt++) {
            #pragma unroll
            for (int kh = 0; kh < 2; kh++) {
                bf16x8 vf = *(bf16x8*)&Vt[buf][kh][(dt*16 + lrow)*32 + quad*8];
                #pragma unroll
                for (int rt = 0; rt < 2; rt++)
                    O[rt][dt] = __builtin_amdgcn_mfma_f32_16x16x32_bf16(pf[rt][kh], vf, O[rt][dt], 0, 0, 0);
            }
        }
    }

    #pragma unroll
    for (int rt = 0; rt < 2; rt++) {
        #pragma unroll
        for (int dt = 0; dt < 4; dt++)
            #pragma unroll
            for (int r = 0; r < 4; r++) {
                const int q = qbase + rt*16 + quad*4 + r;
                Opart[(((size_t)sp*16 + bh)*2048 + q)*64 + dt*16 + lrow] = (__bf16)O[rt][dt][r];
            }
        if (lrow == 0) {
            #pragma unroll
            for (int r = 0; r < 4; r++)
                lpart[((size_t)sp*16 + bh)*2048 + qbase + rt*16 + quad*4 + r] = lacc[rt][r];
        }
    }
}

// ---------------- combine split-K partials -> ctx bf16 ----------------------
__global__ void combine_kernel(const __bf16* __restrict__ Opart, const float* __restrict__ lpart,
                               __bf16* __restrict__ ctx) {
    const int idx = blockIdx.x * 256 + threadIdx.x;   // 16*2048*32 threads
    const int d2 = idx & 31;
    const int q  = (idx >> 5) & 2047;
    const int bh = idx >> 16;
    float ox = 0.0f, oy = 0.0f, l = 0.0f;
    #pragma unroll
    for (int sp = 0; sp < SPLITK; sp++) {
        PkU o; o.u = *((const unsigned*)Opart + (((size_t)sp*16 + bh)*2048 + q)*32 + d2);
        ox += (float)o.h[0]; oy += (float)o.h[1];
        l += lpart[((size_t)sp*16 + bh)*2048 + q];
    }
    const float inv = 1.0f / l;
    PkU pk;
    pk.h[0] = (__bf16)(ox * inv);
    pk.h[1] = (__bf16)(oy * inv);
    const int b = bh >> 3, h = bh & 7;
    *((unsigned*)ctx + (((size_t)b*2048 + q)*512 + h*64) / 2 + d2) = pk.u;
}

// ---------------------------------------------------------------------------
extern "C" void kernel_launch(void* const* d_in, const int* in_sizes, int n_in,
                              void* d_out, int out_size, void* d_ws, size_t ws_size,
                              hipStream_t stream) {
    const float* x    = (const float*)d_in[0];
    const float* n1s  = (const float*)d_in[1];
    const float* n2s  = (const float*)d_in[2];
    const float* wqkv = (const float*)d_in[3];
    const float* bqkv = (const float*)d_in[4];
    const float* wout = (const float*)d_in[5];
    const float* bout = (const float*)d_in[6];
    const float* w1   = (const float*)d_in[7];
    const float* b1   = (const float*)d_in[8];
    const float* w2   = (const float*)d_in[9];
    const float* b2   = (const float*)d_in[10];
    float* out = (float*)d_out;

    char* ws = (char*)d_ws;
    __bf16* xn1    = (__bf16*)ws; ws += (size_t)TOKENS * DMODEL * 2;
    __bf16* qbuf   = (__bf16*)ws; ws += (size_t)TOKENS * DMODEL * 2;
    __bf16* kbuf   = (__bf16*)ws; ws += (size_t)TOKENS * DMODEL * 2;
    __bf16* vtbuf  = (__bf16*)ws; ws += (size_t)TOKENS * DMODEL * 2;
    __bf16* wqkv_b = (__bf16*)ws; ws += (size_t)1536 * DMODEL * 2;
    __bf16* wout_b = (__bf16*)ws; ws += (size_t)DMODEL * DMODEL * 2;
    __bf16* w1_b   = (__bf16*)ws; ws += (size_t)2048 * DMODEL * 2;
    __bf16* w2_b   = (__bf16*)ws; ws += (size_t)DMODEL * 2048 * 2;
    __bf16* ctx    = (__bf16*)ws; ws += (size_t)TOKENS * DMODEL * 2;
    float*  lpart  = (float*)ws;  ws += (size_t)SPLITK * 16 * 2048 * 4;
    __bf16* Opart  = (__bf16*)ws; ws += (size_t)SPLITK * 16 * 2048 * 64 * 2;  // 8.4 MB
    float*  x1     = (float*)ws;  ws += (size_t)TOKENS * DMODEL * 4;
    __bf16* xn2    = (__bf16*)ws; ws += (size_t)TOKENS * DMODEL * 2;
    __bf16* hbuf   = (__bf16*)ws;

    // rmsnorm1 + all weight converts, one launch
    pre_kernel<<<dim3(4096), 256, 0, stream>>>(x, n1s, xn1,
        wqkv, wout, w1, w2, wqkv_b, wout_b, w1_b, w2_b);

    // qkv GEMM (128x128 tiles), epilogue -> q (scaled), k, v-transposed-permuted
    gemm_bt<4, 128><<<dim3(TOKENS / 128, 1536 / 128), 256, 0, stream>>>(
        xn1, wqkv_b, bqkv, nullptr, nullptr, nullptr, qbuf, kbuf, vtbuf,
        TOKENS, 1536, DMODEL);

    attn_kernel<<<dim3(SEQ / 128, 16, SPLITK), 256, 0, stream>>>(
        qbuf, kbuf, vtbuf, Opart, lpart);

    combine_kernel<<<dim3(16 * 2048 * 32 / 256), 256, 0, stream>>>(Opart, lpart, ctx);

    // x1 = x + ctx @ Wout^T + bias
    gemm_bt<1, 32><<<dim3(TOKENS / 32, DMODEL / 128), 256, 0, stream>>>(
        ctx, wout_b, bout, x, x1, nullptr, nullptr, nullptr, nullptr,
        TOKENS, DMODEL, DMODEL);

    rmsnorm_kernel<<<dim3(TOKENS / 4), 256, 0, stream>>>(x1, n2s, xn2);

    // h = gelu(xn2 @ W1^T + b1)
    gemm_bt<2, 128><<<dim3(TOKENS / 128, 2048 / 128), 256, 0, stream>>>(
        xn2, w1_b, b1, nullptr, nullptr, hbuf, nullptr, nullptr, nullptr,
        TOKENS, 2048, DMODEL);

    // out = x1 + h @ W2^T + b2
    gemm_bt<1, 32><<<dim3(TOKENS / 32, DMODEL / 128), 256, 0, stream>>>(
        hbuf, w2_b, b2, x1, out, nullptr, nullptr, nullptr, nullptr,
        TOKENS, DMODEL, 2048);
}